// Round 8
// baseline (1085.015 us; speedup 1.0000x reference)
//
#include <hip/hip_runtime.h>

#define TT 256
#define VV 95

__device__ __forceinline__ float fast_sigmoid(float v) {
    return __builtin_amdgcn_rcpf(1.0f + __expf(-v));
}
__device__ __forceinline__ float fast_tanh(float v) {
    return 1.0f - 2.0f * __builtin_amdgcn_rcpf(__expf(2.0f * v) + 1.0f);
}
// broadcast lane k of v to all lanes (SGPR result) — VALU, no DS
__device__ __forceinline__ float RLf(float v, int lane) {
    return __int_as_float(__builtin_amdgcn_readlane(__float_as_int(v), lane));
}
// partner (lane^32) exchange — ds_bpermute path, VERIFIED in R3/R5/R6 kernels.
// (R7's v_permlane32_swap inline asm was the prime correctness suspect.)
__device__ __forceinline__ float partner32(float x) {
    return __shfl_xor(x, 32);
}

// ---- fallback-path helpers (no-ws k1 variant only) ----
__device__ __forceinline__ void wave_fence() {
    asm volatile("s_waitcnt lgkmcnt(0)" ::: "memory");
    __builtin_amdgcn_wave_barrier();
}
__device__ __forceinline__ void vm_wait0() {
    asm volatile("s_waitcnt vmcnt(0)" ::: "memory");
}
__device__ __forceinline__ void gld_lds4(const float* g, float* lds) {
    __builtin_amdgcn_global_load_lds(
        (const __attribute__((address_space(1))) void*)g,
        (__attribute__((address_space(3))) void*)lds,
        4, 0, 0);
}
__device__ __forceinline__ void stage760(const float* g, float* lds, int l) {
    #pragma unroll
    for (int i = 0; i < 11; ++i) gld_lds4(g + i * 64 + l, lds + i * 64);
    if (l < 56) gld_lds4(g + 704 + l, lds + 704);
}
__device__ __forceinline__ float dot16(const float* w, float4 a, float4 b, float4 c, float4 d) {
    float s = 0.0f;
    s = fmaf(w[0],  a.x, s); s = fmaf(w[1],  a.y, s); s = fmaf(w[2],  a.z, s); s = fmaf(w[3],  a.w, s);
    s = fmaf(w[4],  b.x, s); s = fmaf(w[5],  b.y, s); s = fmaf(w[6],  b.z, s); s = fmaf(w[7],  b.w, s);
    s = fmaf(w[8],  c.x, s); s = fmaf(w[9],  c.y, s); s = fmaf(w[10], c.z, s); s = fmaf(w[11], c.w, s);
    s = fmaf(w[12], d.x, s); s = fmaf(w[13], d.y, s); s = fmaf(w[14], d.z, s); s = fmaf(w[15], d.w, s);
    return s;
}

// ================= K0: xp = x @ Wih1^T + bih1 -> out cols 0:95; gate 95 -> ws (if avail)
__global__ void __launch_bounds__(256) k0_xproj(
    const float* __restrict__ x, const float* __restrict__ Wih1,
    const float* __restrict__ bih1, float* __restrict__ out,
    float* __restrict__ ws95, int use_ws)
{
    __shared__ float xs[64 * 100];
    __shared__ float ws[96 * 100];
    const int tid = threadIdx.x;
    const size_t row0 = (size_t)blockIdx.x * 64;

    const float* xg = x + row0 * VV;
    for (int i = tid; i < 64 * VV; i += 256) {
        const int r = i / VV, c = i - r * VV;
        xs[r * 100 + c] = xg[i];
    }
    for (int i = tid; i < 96 * VV; i += 256) {
        const int g = i / VV, c = i - g * VV;
        ws[g * 100 + c] = Wih1[i];
    }
    for (int i = tid; i < 64 * 5; i += 256) xs[(i / 5) * 100 + 95 + (i % 5)] = 0.f;
    for (int i = tid; i < 96 * 5; i += 256) ws[(i / 5) * 100 + 95 + (i % 5)] = 0.f;

    const int cq = tid & 15, rq = tid >> 4;
    float acc[4][6];
    #pragma unroll
    for (int c = 0; c < 6; ++c) {
        const float bv = bih1[cq + 16 * c];
        acc[0][c] = bv; acc[1][c] = bv; acc[2][c] = bv; acc[3][c] = bv;
    }
    __syncthreads();

    const float* xp0 = xs + rq * 100;
    const float* wp0 = ws + cq * 100;
    #pragma unroll 4
    for (int k4 = 0; k4 < 24; ++k4) {
        const int k = k4 * 4;
        float4 xv0 = *(const float4*)(xp0 + k);
        float4 xv1 = *(const float4*)(xp0 + 1600 + k);
        float4 xv2 = *(const float4*)(xp0 + 3200 + k);
        float4 xv3 = *(const float4*)(xp0 + 4800 + k);
        #pragma unroll
        for (int c = 0; c < 6; ++c) {
            const float4 wv = *(const float4*)(wp0 + c * 1600 + k);
            acc[0][c] = fmaf(xv0.x, wv.x, acc[0][c]); acc[0][c] = fmaf(xv0.y, wv.y, acc[0][c]);
            acc[0][c] = fmaf(xv0.z, wv.z, acc[0][c]); acc[0][c] = fmaf(xv0.w, wv.w, acc[0][c]);
            acc[1][c] = fmaf(xv1.x, wv.x, acc[1][c]); acc[1][c] = fmaf(xv1.y, wv.y, acc[1][c]);
            acc[1][c] = fmaf(xv1.z, wv.z, acc[1][c]); acc[1][c] = fmaf(xv1.w, wv.w, acc[1][c]);
            acc[2][c] = fmaf(xv2.x, wv.x, acc[2][c]); acc[2][c] = fmaf(xv2.y, wv.y, acc[2][c]);
            acc[2][c] = fmaf(xv2.z, wv.z, acc[2][c]); acc[2][c] = fmaf(xv2.w, wv.w, acc[2][c]);
            acc[3][c] = fmaf(xv3.x, wv.x, acc[3][c]); acc[3][c] = fmaf(xv3.y, wv.y, acc[3][c]);
            acc[3][c] = fmaf(xv3.z, wv.z, acc[3][c]); acc[3][c] = fmaf(xv3.w, wv.w, acc[3][c]);
        }
    }
    #pragma unroll
    for (int r = 0; r < 4; ++r) {
        float* orow = out + (row0 + rq + 16 * r) * VV;
        #pragma unroll
        for (int c = 0; c < 6; ++c) {
            const int g = cq + 16 * c;
            if (g < VV) orow[g] = acc[r][c];
            else if (use_ws) ws95[row0 + rq + 16 * r] = acc[r][c];   // g==95
        }
    }
}

// ================= K1 (primary): L1 recurrence, SGPR-broadcast h, zero LDS state.
// lanes 0-31: r gate + n hidden-dot; lanes 32-63: z gate (zero-padded wB).
#define L1S(tt, A, N, Wv) do {                                          \
    float nA = 0.f, nN = 0.f, nW = 0.f;                                 \
    if ((tt) + 4 < TT) {                                                \
        nA = orow[((tt) + 4) * VV + l];                                 \
        nN = orow[((tt) + 4) * VV + nidx];                              \
        nW = wsrow[(tt) + 4];                                           \
    }                                                                   \
    float a0 = bA, a1 = 0.f, b0 = bB, b1 = 0.f;                         \
    _Pragma("unroll")                                                   \
    for (int k = 0; k < 32; k += 2) {                                   \
        const float s0 = RLf(vh, k), s1 = RLf(vh, k + 1);               \
        a0 = fmaf(wA[k], s0, a0);   a1 = fmaf(wA[k + 1], s1, a1);       \
        b0 = fmaf(wB[k], s0, b0);   b1 = fmaf(wB[k + 1], s1, b1);       \
    }                                                                   \
    const float val = (A) + a0 + a1;                                    \
    const float oA = partner32(val);                                    \
    const float r_ = fast_sigmoid(val);                                 \
    const float z_ = fast_sigmoid(oA);                                  \
    const float xn_ = (j == 31) ? (Wv) : (N);                           \
    const float n_ = fast_tanh(xn_ + r_ * (b0 + b1));                   \
    hj = (1.f - z_) * n_ + z_ * hj;                                     \
    vh = hj;                                                            \
    if (l < 32) orow[(tt) * VV + j] = hj;                               \
    (A) = nA; (N) = nN; (Wv) = nW;                                      \
} while (0)

extern "C" __global__ void __launch_bounds__(256) k1_sgpr(
    const float* __restrict__ Whh1, const float* __restrict__ bhh1,
    const float* __restrict__ ws95, float* __restrict__ out)
{
    const int tid = threadIdx.x;
    const int w = tid >> 6, l = tid & 63, j = l & 31;
    const bool hi = l >= 32;

    float wA[32], wB[32];
    const int rA = (hi ? 32 : 0) + j;
    #pragma unroll
    for (int k = 0; k < 32; ++k) {
        wA[k] = Whh1[rA * 32 + k];                       // Whr (lo) / Whz (hi)
        wB[k] = hi ? 0.f : Whh1[(64 + j) * 32 + k];      // Whn (lo only)
    }
    const float bA = bhh1[rA];
    const float bB = bhh1[64 + j];

    const size_t b = (size_t)blockIdx.x * 4 + w;
    float* orow = out + b * (size_t)(TT * VV);
    const float* wsrow = ws95 + b * TT;

    float vh = 0.f, hj = 0.f;
    const int nidx = 64 + (j < 31 ? j : 30);             // lane31's slot comes from ws
    float A0 = orow[0 * VV + l], N0 = orow[0 * VV + nidx], W0 = wsrow[0];
    float A1 = orow[1 * VV + l], N1 = orow[1 * VV + nidx], W1 = wsrow[1];
    float A2 = orow[2 * VV + l], N2 = orow[2 * VV + nidx], W2 = wsrow[2];
    float A3 = orow[3 * VV + l], N3 = orow[3 * VV + nidx], W3 = wsrow[3];

    for (int t = 0; t < TT; t += 4) {
        L1S(t + 0, A0, N0, W0);
        L1S(t + 1, A1, N1, W1);
        L1S(t + 2, A2, N2, W2);
        L1S(t + 3, A3, N3, W3);
    }
}

// ================= K1 (fallback, ws too small): R6 structure with x butterfly
extern "C" __global__ void __launch_bounds__(256, 2) k1_l1_fb(
    const float* __restrict__ x, const float* __restrict__ Wih1,
    const float* __restrict__ Whh1, const float* __restrict__ bih1,
    const float* __restrict__ bhh1, float* __restrict__ out)
{
    __shared__ __align__(16) float xpb[4][2][768];
    __shared__ __align__(16) float xb [4][2][768];
    __shared__ __align__(16) float hb[4][32];

    const int tid = threadIdx.x;
    const int w = tid >> 6, l = tid & 63, p = l >> 5, j = l & 31;

    float ur[16], uz[16], un[16];
    #pragma unroll
    for (int c = 0; c < 16; ++c) {
        ur[c] = Whh1[j * 32 + 16 * p + c];
        uz[c] = Whh1[(32 + j) * 32 + 16 * p + c];
        un[c] = Whh1[(64 + j) * 32 + 16 * p + c];
    }
    const float bhr = bhh1[j], bhz = bhh1[32 + j], bhn = bhh1[64 + j];
    const float wa = Wih1[95 * VV + l];
    const float wb = (l < 31) ? Wih1[95 * VV + 64 + l] : 0.f;
    const float bn95 = bih1[95];

    const size_t b = (size_t)blockIdx.x * 4 + w;
    const float* xrow = x + b * (size_t)(TT * VV);
    float* orow = out + b * (size_t)(TT * VV);

    if (p == 0) hb[w][j] = 0.f;
    float hj = 0.f;

    stage760(orow, &xpb[w][0][0], l);
    stage760(xrow, &xb[w][0][0], l);
    wave_fence();

    for (int t = 0; t < TT; ++t) {
        const int tc = t & 7;
        const int cb = (t >> 3) & 1;
        if (tc == 0) {
            vm_wait0();
            if (t + 8 < TT) {
                stage760(orow + (t + 8) * VV, &xpb[w][cb ^ 1][0], l);
                stage760(xrow + (t + 8) * VV, &xb[w][cb ^ 1][0], l);
            }
        }
        const float* xpc = &xpb[w][cb][tc * VV];
        const float* xc  = &xb [w][cb][tc * VV];
        const float xr  = xpc[j];
        const float xz  = xpc[32 + j];
        const float xn  = (j < 31) ? xpc[64 + j] : 0.f;
        const float xav = xc[l];
        const float xbv = (l < 31) ? xc[64 + l] : 0.f;

        float v = fmaf(wa, xav, wb * xbv);
        v += __shfl_xor(v, 1);  v += __shfl_xor(v, 2);  v += __shfl_xor(v, 4);
        v += __shfl_xor(v, 8);  v += __shfl_xor(v, 16); v += __shfl_xor(v, 32);

        const float4* hv = (const float4*)(&hb[w][16 * p]);
        const float4 h0 = hv[0], h1v = hv[1], h2v = hv[2], h3v = hv[3];
        float hr = dot16(ur, h0, h1v, h2v, h3v);
        float hz = dot16(uz, h0, h1v, h2v, h3v);
        float hn = dot16(un, h0, h1v, h2v, h3v);
        hr += __shfl_xor(hr, 32);
        hz += __shfl_xor(hz, 32);
        hn += __shfl_xor(hn, 32);

        const float xnf = (j == 31) ? (v + bn95) : xn;
        const float r = fast_sigmoid(xr + hr + bhr);
        const float z = fast_sigmoid(xz + hz + bhz);
        const float n = fast_tanh(xnf + r * (hn + bhn));
        hj = (1.0f - z) * n + z * hj;

        asm volatile("" ::: "memory");
        if (p == 0) { hb[w][j] = hj; orow[t * VV + j] = hj; }
        wave_fence();
    }
}

// ================= K23: generic 32->32 GRU layer, SGPR-broadcast, zero LDS state.
// lanes 0-31: r + n-input-dot; lanes 32-63: z + n-hidden-dot (zero-padded).
#define K23S(tt, VIN) do {                                              \
    float nI = 0.f;                                                     \
    if ((tt) + 4 < TT) nI = irow[((tt) + 4) * VV + j];                  \
    float a0 = bA, a1 = 0.f, c0 = bN, c1 = 0.f;                         \
    _Pragma("unroll")                                                   \
    for (int k = 0; k < 32; k += 2) {                                   \
        const float i0 = RLf(VIN, k),     h0 = RLf(vh, k);              \
        const float i1 = RLf(VIN, k + 1), h1 = RLf(vh, k + 1);          \
        a0 = fmaf(wI[k], i0, a0);      a0 = fmaf(wH[k], h0, a0);        \
        a1 = fmaf(wI[k + 1], i1, a1);  a1 = fmaf(wH[k + 1], h1, a1);    \
        c0 = fmaf(wNI[k], i0, c0);     c0 = fmaf(wNH[k], h0, c0);       \
        c1 = fmaf(wNI[k + 1], i1, c1); c1 = fmaf(wNH[k + 1], h1, c1);   \
    }                                                                   \
    const float valA = a0 + a1, valC = c0 + c1;                         \
    const float oA = partner32(valA);                                   \
    const float oC = partner32(valC);                                   \
    const float r_ = fast_sigmoid(valA);                                \
    const float z_ = fast_sigmoid(oA);                                  \
    const float n_ = fast_tanh(valC + r_ * oC);                         \
    hj = (1.f - z_) * n_ + z_ * hj;                                     \
    vh = hj;                                                            \
    if (l < 32) orow[(tt) * VV + out_col + j] = hj;                     \
    (VIN) = nI;                                                         \
} while (0)

extern "C" __global__ void __launch_bounds__(256) k23_sgpr(
    const float* __restrict__ Wih, const float* __restrict__ Whh,
    const float* __restrict__ bih, const float* __restrict__ bhh,
    float* __restrict__ out, int in_col, int out_col)
{
    const int tid = threadIdx.x;
    const int w = tid >> 6, l = tid & 63, j = l & 31;
    const bool hi = l >= 32;

    float wI[32], wH[32], wNI[32], wNH[32];
    const int rA = (hi ? 32 : 0) + j;
    #pragma unroll
    for (int k = 0; k < 32; ++k) {
        wI[k]  = Wih[rA * 32 + k];                        // Wir / Wiz
        wH[k]  = Whh[rA * 32 + k];                        // Whr / Whz
        wNI[k] = hi ? 0.f : Wih[(64 + j) * 32 + k];       // Win (lo)
        wNH[k] = hi ? Whh[(64 + j) * 32 + k] : 0.f;       // Whn (hi)
    }
    const float bA = bih[rA] + bhh[rA];
    const float bN = hi ? bhh[64 + j] : bih[64 + j];

    const size_t b = (size_t)blockIdx.x * 4 + w;
    float* orow = out + b * (size_t)(TT * VV);
    const float* irow = orow + in_col;

    float vh = 0.f, hj = 0.f;
    float I0 = irow[0 * VV + j], I1 = irow[1 * VV + j];
    float I2 = irow[2 * VV + j], I3 = irow[3 * VV + j];

    for (int t = 0; t < TT; t += 4) {
        K23S(t + 0, I0);
        K23S(t + 1, I1);
        K23S(t + 2, I2);
        K23S(t + 3, I3);
    }
}

// ================= K4: FC GEMM. reads h3 from cols 0:32, writes all 95 cols in-place
__global__ void __launch_bounds__(256) k4_fc(
    const float* __restrict__ Wfc, const float* __restrict__ bfc,
    float* __restrict__ out)
{
    __shared__ float hs[64 * 36];
    __shared__ float ws[96 * 36];
    const int tid = threadIdx.x;
    const size_t row0 = (size_t)blockIdx.x * 64;

    for (int i = tid; i < 64 * 32; i += 256) {
        const int r = i >> 5, k = i & 31;
        hs[r * 36 + k] = out[(row0 + r) * VV + k];
    }
    for (int i = tid; i < 95 * 32; i += 256) {
        const int g = i >> 5, k = i & 31;
        ws[g * 36 + k] = Wfc[i];
    }
    for (int i = tid; i < 32; i += 256) ws[95 * 36 + i] = 0.f;
    const int cq = tid & 15, rq = tid >> 4;
    float acc[4][6];
    #pragma unroll
    for (int c = 0; c < 6; ++c) {
        const int g = cq + 16 * c;
        const float bv = (g < VV) ? bfc[g] : 0.f;
        acc[0][c] = bv; acc[1][c] = bv; acc[2][c] = bv; acc[3][c] = bv;
    }
    __syncthreads();

    #pragma unroll
    for (int k4 = 0; k4 < 8; ++k4) {
        const int k = k4 * 4;
        const float4 h0 = *(const float4*)(hs + (rq     ) * 36 + k);
        const float4 h1 = *(const float4*)(hs + (rq + 16) * 36 + k);
        const float4 h2 = *(const float4*)(hs + (rq + 32) * 36 + k);
        const float4 h3 = *(const float4*)(hs + (rq + 48) * 36 + k);
        #pragma unroll
        for (int c = 0; c < 6; ++c) {
            const float4 wv = *(const float4*)(ws + (cq + 16 * c) * 36 + k);
            acc[0][c] = fmaf(h0.x, wv.x, acc[0][c]); acc[0][c] = fmaf(h0.y, wv.y, acc[0][c]);
            acc[0][c] = fmaf(h0.z, wv.z, acc[0][c]); acc[0][c] = fmaf(h0.w, wv.w, acc[0][c]);
            acc[1][c] = fmaf(h1.x, wv.x, acc[1][c]); acc[1][c] = fmaf(h1.y, wv.y, acc[1][c]);
            acc[1][c] = fmaf(h1.z, wv.z, acc[1][c]); acc[1][c] = fmaf(h1.w, wv.w, acc[1][c]);
            acc[2][c] = fmaf(h2.x, wv.x, acc[2][c]); acc[2][c] = fmaf(h2.y, wv.y, acc[2][c]);
            acc[2][c] = fmaf(h2.z, wv.z, acc[2][c]); acc[2][c] = fmaf(h2.w, wv.w, acc[2][c]);
            acc[3][c] = fmaf(h3.x, wv.x, acc[3][c]); acc[3][c] = fmaf(h3.y, wv.y, acc[3][c]);
            acc[3][c] = fmaf(h3.z, wv.z, acc[3][c]); acc[3][c] = fmaf(h3.w, wv.w, acc[3][c]);
        }
    }
    #pragma unroll
    for (int r = 0; r < 4; ++r) {
        float* orow = out + (row0 + rq + 16 * r) * VV;
        #pragma unroll
        for (int c = 0; c < 6; ++c) {
            const int g = cq + 16 * c;
            if (g < VV) orow[g] = acc[r][c];
        }
    }
}

extern "C" void kernel_launch(void* const* d_in, const int* in_sizes, int n_in,
                              void* d_out, int out_size, void* d_ws, size_t ws_size,
                              hipStream_t stream) {
    const float* x    = (const float*)d_in[0];
    const float* Wih1 = (const float*)d_in[1];
    const float* Whh1 = (const float*)d_in[2];
    const float* bih1 = (const float*)d_in[3];
    const float* bhh1 = (const float*)d_in[4];
    const float* Wih2 = (const float*)d_in[5];
    const float* Whh2 = (const float*)d_in[6];
    const float* bih2 = (const float*)d_in[7];
    const float* bhh2 = (const float*)d_in[8];
    const float* Wih3 = (const float*)d_in[9];
    const float* Whh3 = (const float*)d_in[10];
    const float* bih3 = (const float*)d_in[11];
    const float* bhh3 = (const float*)d_in[12];
    const float* Wfc  = (const float*)d_in[13];
    const float* bfc  = (const float*)d_in[14];
    float* out = (float*)d_out;
    float* ws95 = (float*)d_ws;

    const int use_ws = (ws_size >= (size_t)2048 * 256 * 4) ? 1 : 0;

    hipLaunchKernelGGL(k0_xproj, dim3(8192), dim3(256), 0, stream,
                       x, Wih1, bih1, out, ws95, use_ws);
    if (use_ws)
        hipLaunchKernelGGL(k1_sgpr, dim3(512), dim3(256), 0, stream, Whh1, bhh1, ws95, out);
    else
        hipLaunchKernelGGL(k1_l1_fb, dim3(512), dim3(256), 0, stream,
                           x, Wih1, Whh1, bih1, bhh1, out);
    hipLaunchKernelGGL(k23_sgpr, dim3(512), dim3(256), 0, stream,
                       Wih2, Whh2, bih2, bhh2, out, 0, 32);
    hipLaunchKernelGGL(k23_sgpr, dim3(512), dim3(256), 0, stream,
                       Wih3, Whh3, bih3, bhh3, out, 32, 0);
    hipLaunchKernelGGL(k4_fc, dim3(8192), dim3(256), 0, stream, Wfc, bfc, out);
}

// Round 9
// 1049.730 us; speedup vs baseline: 1.0336x; 1.0336x over previous
//
#include <hip/hip_runtime.h>

#define TT 256
#define VV 95

__device__ __forceinline__ float fast_sigmoid(float v) {
    return __builtin_amdgcn_rcpf(1.0f + __expf(-v));
}
__device__ __forceinline__ float fast_tanh(float v) {
    return 1.0f - 2.0f * __builtin_amdgcn_rcpf(__expf(2.0f * v) + 1.0f);
}
// broadcast lane k of v to all lanes (SGPR result) — VALU, no DS
__device__ __forceinline__ float RLf(float v, int lane) {
    return __int_as_float(__builtin_amdgcn_readlane(__float_as_int(v), lane));
}
// partner (lane^32) exchange — ds_bpermute path, verified R3/R5/R6/R8.
__device__ __forceinline__ float partner32(float x) {
    return __shfl_xor(x, 32);
}
// pin a value into an architectural VGPR (defeat AGPR/rematerialization choices)
#define KEEPV(x) asm volatile("" : "+v"(x))

// ---- fallback-path helpers (no-ws k1 variant only) ----
__device__ __forceinline__ void wave_fence() {
    asm volatile("s_waitcnt lgkmcnt(0)" ::: "memory");
    __builtin_amdgcn_wave_barrier();
}
__device__ __forceinline__ void vm_wait0() {
    asm volatile("s_waitcnt vmcnt(0)" ::: "memory");
}
__device__ __forceinline__ void gld_lds4(const float* g, float* lds) {
    __builtin_amdgcn_global_load_lds(
        (const __attribute__((address_space(1))) void*)g,
        (__attribute__((address_space(3))) void*)lds,
        4, 0, 0);
}
__device__ __forceinline__ void stage760(const float* g, float* lds, int l) {
    #pragma unroll
    for (int i = 0; i < 11; ++i) gld_lds4(g + i * 64 + l, lds + i * 64);
    if (l < 56) gld_lds4(g + 704 + l, lds + 704);
}
__device__ __forceinline__ float dot16(const float* w, float4 a, float4 b, float4 c, float4 d) {
    float s = 0.0f;
    s = fmaf(w[0],  a.x, s); s = fmaf(w[1],  a.y, s); s = fmaf(w[2],  a.z, s); s = fmaf(w[3],  a.w, s);
    s = fmaf(w[4],  b.x, s); s = fmaf(w[5],  b.y, s); s = fmaf(w[6],  b.z, s); s = fmaf(w[7],  b.w, s);
    s = fmaf(w[8],  c.x, s); s = fmaf(w[9],  c.y, s); s = fmaf(w[10], c.z, s); s = fmaf(w[11], c.w, s);
    s = fmaf(w[12], d.x, s); s = fmaf(w[13], d.y, s); s = fmaf(w[14], d.z, s); s = fmaf(w[15], d.w, s);
    return s;
}

// ================= K0: xp = x @ Wih1^T + bih1 -> out cols 0:95; gate 95 -> ws (if avail)
__global__ void __launch_bounds__(256) k0_xproj(
    const float* __restrict__ x, const float* __restrict__ Wih1,
    const float* __restrict__ bih1, float* __restrict__ out,
    float* __restrict__ ws95, int use_ws)
{
    __shared__ float xs[64 * 100];
    __shared__ float ws[96 * 100];
    const int tid = threadIdx.x;
    const size_t row0 = (size_t)blockIdx.x * 64;

    const float* xg = x + row0 * VV;
    for (int i = tid; i < 64 * VV; i += 256) {
        const int r = i / VV, c = i - r * VV;
        xs[r * 100 + c] = xg[i];
    }
    for (int i = tid; i < 96 * VV; i += 256) {
        const int g = i / VV, c = i - g * VV;
        ws[g * 100 + c] = Wih1[i];
    }
    for (int i = tid; i < 64 * 5; i += 256) xs[(i / 5) * 100 + 95 + (i % 5)] = 0.f;
    for (int i = tid; i < 96 * 5; i += 256) ws[(i / 5) * 100 + 95 + (i % 5)] = 0.f;

    const int cq = tid & 15, rq = tid >> 4;
    float acc[4][6];
    #pragma unroll
    for (int c = 0; c < 6; ++c) {
        const float bv = bih1[cq + 16 * c];
        acc[0][c] = bv; acc[1][c] = bv; acc[2][c] = bv; acc[3][c] = bv;
    }
    __syncthreads();

    const float* xp0 = xs + rq * 100;
    const float* wp0 = ws + cq * 100;
    #pragma unroll 4
    for (int k4 = 0; k4 < 24; ++k4) {
        const int k = k4 * 4;
        float4 xv0 = *(const float4*)(xp0 + k);
        float4 xv1 = *(const float4*)(xp0 + 1600 + k);
        float4 xv2 = *(const float4*)(xp0 + 3200 + k);
        float4 xv3 = *(const float4*)(xp0 + 4800 + k);
        #pragma unroll
        for (int c = 0; c < 6; ++c) {
            const float4 wv = *(const float4*)(wp0 + c * 1600 + k);
            acc[0][c] = fmaf(xv0.x, wv.x, acc[0][c]); acc[0][c] = fmaf(xv0.y, wv.y, acc[0][c]);
            acc[0][c] = fmaf(xv0.z, wv.z, acc[0][c]); acc[0][c] = fmaf(xv0.w, wv.w, acc[0][c]);
            acc[1][c] = fmaf(xv1.x, wv.x, acc[1][c]); acc[1][c] = fmaf(xv1.y, wv.y, acc[1][c]);
            acc[1][c] = fmaf(xv1.z, wv.z, acc[1][c]); acc[1][c] = fmaf(xv1.w, wv.w, acc[1][c]);
            acc[2][c] = fmaf(xv2.x, wv.x, acc[2][c]); acc[2][c] = fmaf(xv2.y, wv.y, acc[2][c]);
            acc[2][c] = fmaf(xv2.z, wv.z, acc[2][c]); acc[2][c] = fmaf(xv2.w, wv.w, acc[2][c]);
            acc[3][c] = fmaf(xv3.x, wv.x, acc[3][c]); acc[3][c] = fmaf(xv3.y, wv.y, acc[3][c]);
            acc[3][c] = fmaf(xv3.z, wv.z, acc[3][c]); acc[3][c] = fmaf(xv3.w, wv.w, acc[3][c]);
        }
    }
    #pragma unroll
    for (int r = 0; r < 4; ++r) {
        float* orow = out + (row0 + rq + 16 * r) * VV;
        #pragma unroll
        for (int c = 0; c < 6; ++c) {
            const int g = cq + 16 * c;
            if (g < VV) orow[g] = acc[r][c];
            else if (use_ws) ws95[row0 + rq + 16 * r] = acc[r][c];   // g==95
        }
    }
}

// ================= K1 (primary): L1 recurrence, SGPR-broadcast h, zero LDS state.
// lanes 0-31: r gate + n hidden-dot; lanes 32-63: z gate (zero-padded wB).
#define L1S(tt, A, N, Wv) do {                                          \
    float nA = 0.f, nN = 0.f, nW = 0.f;                                 \
    if ((tt) + 4 < TT) {                                                \
        nA = orow[((tt) + 4) * VV + l];                                 \
        nN = orow[((tt) + 4) * VV + nidx];                              \
        nW = wsrow[(tt) + 4];                                           \
    }                                                                   \
    float a0 = bA, a1 = 0.f, b0 = bB, b1 = 0.f;                         \
    _Pragma("unroll")                                                   \
    for (int k = 0; k < 32; k += 2) {                                   \
        const float s0 = RLf(vh, k), s1 = RLf(vh, k + 1);               \
        a0 = fmaf(wA[k], s0, a0);   a1 = fmaf(wA[k + 1], s1, a1);       \
        b0 = fmaf(wB[k], s0, b0);   b1 = fmaf(wB[k + 1], s1, b1);       \
    }                                                                   \
    const float val = (A) + a0 + a1;                                    \
    const float oA = partner32(val);                                    \
    const float r_ = fast_sigmoid(val);                                 \
    const float z_ = fast_sigmoid(oA);                                  \
    const float xn_ = (j == 31) ? (Wv) : (N);                           \
    const float n_ = fast_tanh(xn_ + r_ * (b0 + b1));                   \
    hj = (1.f - z_) * n_ + z_ * hj;                                     \
    vh = hj;                                                            \
    if (l < 32) orow[(tt) * VV + j] = hj;                               \
    (A) = nA; (N) = nN; (Wv) = nW;                                      \
} while (0)

extern "C" __global__ void __launch_bounds__(256, 2) k1_sgpr(
    const float* __restrict__ Whh1, const float* __restrict__ bhh1,
    const float* __restrict__ ws95, float* __restrict__ out)
{
    const int tid = threadIdx.x;
    const int w = tid >> 6, l = tid & 63, j = l & 31;
    const bool hi = l >= 32;

    float wA[32], wB[32];
    const int rA = (hi ? 32 : 0) + j;
    #pragma unroll
    for (int k = 0; k < 32; ++k) {
        wA[k] = Whh1[rA * 32 + k];                       // Whr (lo) / Whz (hi)
        wB[k] = hi ? 0.f : Whh1[(64 + j) * 32 + k];      // Whn (lo only)
    }
    #pragma unroll
    for (int k = 0; k < 32; ++k) { KEEPV(wA[k]); KEEPV(wB[k]); }
    const float bA = bhh1[rA];
    const float bB = bhh1[64 + j];

    const size_t b = (size_t)blockIdx.x * 4 + w;
    float* orow = out + b * (size_t)(TT * VV);
    const float* wsrow = ws95 + b * TT;

    float vh = 0.f, hj = 0.f;
    const int nidx = 64 + (j < 31 ? j : 30);             // lane31's slot comes from ws
    float A0 = orow[0 * VV + l], N0 = orow[0 * VV + nidx], W0 = wsrow[0];
    float A1 = orow[1 * VV + l], N1 = orow[1 * VV + nidx], W1 = wsrow[1];
    float A2 = orow[2 * VV + l], N2 = orow[2 * VV + nidx], W2 = wsrow[2];
    float A3 = orow[3 * VV + l], N3 = orow[3 * VV + nidx], W3 = wsrow[3];

    for (int t = 0; t < TT; t += 4) {
        L1S(t + 0, A0, N0, W0);
        L1S(t + 1, A1, N1, W1);
        L1S(t + 2, A2, N2, W2);
        L1S(t + 3, A3, N3, W3);
    }
}

// ================= K1 (fallback, ws too small): R6 structure with x butterfly
extern "C" __global__ void __launch_bounds__(256, 2) k1_l1_fb(
    const float* __restrict__ x, const float* __restrict__ Wih1,
    const float* __restrict__ Whh1, const float* __restrict__ bih1,
    const float* __restrict__ bhh1, float* __restrict__ out)
{
    __shared__ __align__(16) float xpb[4][2][768];
    __shared__ __align__(16) float xb [4][2][768];
    __shared__ __align__(16) float hb[4][32];

    const int tid = threadIdx.x;
    const int w = tid >> 6, l = tid & 63, p = l >> 5, j = l & 31;

    float ur[16], uz[16], un[16];
    #pragma unroll
    for (int c = 0; c < 16; ++c) {
        ur[c] = Whh1[j * 32 + 16 * p + c];
        uz[c] = Whh1[(32 + j) * 32 + 16 * p + c];
        un[c] = Whh1[(64 + j) * 32 + 16 * p + c];
    }
    const float bhr = bhh1[j], bhz = bhh1[32 + j], bhn = bhh1[64 + j];
    const float wa = Wih1[95 * VV + l];
    const float wb = (l < 31) ? Wih1[95 * VV + 64 + l] : 0.f;
    const float bn95 = bih1[95];

    const size_t b = (size_t)blockIdx.x * 4 + w;
    const float* xrow = x + b * (size_t)(TT * VV);
    float* orow = out + b * (size_t)(TT * VV);

    if (p == 0) hb[w][j] = 0.f;
    float hj = 0.f;

    stage760(orow, &xpb[w][0][0], l);
    stage760(xrow, &xb[w][0][0], l);
    wave_fence();

    for (int t = 0; t < TT; ++t) {
        const int tc = t & 7;
        const int cb = (t >> 3) & 1;
        if (tc == 0) {
            vm_wait0();
            if (t + 8 < TT) {
                stage760(orow + (t + 8) * VV, &xpb[w][cb ^ 1][0], l);
                stage760(xrow + (t + 8) * VV, &xb[w][cb ^ 1][0], l);
            }
        }
        const float* xpc = &xpb[w][cb][tc * VV];
        const float* xc  = &xb [w][cb][tc * VV];
        const float xr  = xpc[j];
        const float xz  = xpc[32 + j];
        const float xn  = (j < 31) ? xpc[64 + j] : 0.f;
        const float xav = xc[l];
        const float xbv = (l < 31) ? xc[64 + l] : 0.f;

        float v = fmaf(wa, xav, wb * xbv);
        v += __shfl_xor(v, 1);  v += __shfl_xor(v, 2);  v += __shfl_xor(v, 4);
        v += __shfl_xor(v, 8);  v += __shfl_xor(v, 16); v += __shfl_xor(v, 32);

        const float4* hv = (const float4*)(&hb[w][16 * p]);
        const float4 h0 = hv[0], h1v = hv[1], h2v = hv[2], h3v = hv[3];
        float hr = dot16(ur, h0, h1v, h2v, h3v);
        float hz = dot16(uz, h0, h1v, h2v, h3v);
        float hn = dot16(un, h0, h1v, h2v, h3v);
        hr += __shfl_xor(hr, 32);
        hz += __shfl_xor(hz, 32);
        hn += __shfl_xor(hn, 32);

        const float xnf = (j == 31) ? (v + bn95) : xn;
        const float r = fast_sigmoid(xr + hr + bhr);
        const float z = fast_sigmoid(xz + hz + bhz);
        const float n = fast_tanh(xnf + r * (hn + bhn));
        hj = (1.0f - z) * n + z * hj;

        asm volatile("" ::: "memory");
        if (p == 0) { hb[w][j] = hj; orow[t * VV + j] = hj; }
        wave_fence();
    }
}

// ================= K23: generic 32->32 GRU layer, SGPR-broadcast, zero LDS state.
// lanes 0-31: r + n-input-dot; lanes 32-63: z + n-hidden-dot (zero-padded).
#define K23S(tt, VIN) do {                                              \
    float nI = 0.f;                                                     \
    if ((tt) + 4 < TT) nI = irow[((tt) + 4) * VV + j];                  \
    float a0 = bA, a1 = 0.f, c0 = bN, c1 = 0.f;                         \
    _Pragma("unroll")                                                   \
    for (int k = 0; k < 32; k += 2) {                                   \
        const float i0 = RLf(VIN, k),     h0 = RLf(vh, k);              \
        const float i1 = RLf(VIN, k + 1), h1 = RLf(vh, k + 1);          \
        a0 = fmaf(wI[k], i0, a0);      a0 = fmaf(wH[k], h0, a0);        \
        a1 = fmaf(wI[k + 1], i1, a1);  a1 = fmaf(wH[k + 1], h1, a1);    \
        c0 = fmaf(wNI[k], i0, c0);     c0 = fmaf(wNH[k], h0, c0);       \
        c1 = fmaf(wNI[k + 1], i1, c1); c1 = fmaf(wNH[k + 1], h1, c1);   \
    }                                                                   \
    const float valA = a0 + a1, valC = c0 + c1;                         \
    const float oA = partner32(valA);                                   \
    const float oC = partner32(valC);                                   \
    const float r_ = fast_sigmoid(valA);                                \
    const float z_ = fast_sigmoid(oA);                                  \
    const float n_ = fast_tanh(valC + r_ * oC);                         \
    hj = (1.f - z_) * n_ + z_ * hj;                                     \
    vh = hj;                                                            \
    if (l < 32) orow[(tt) * VV + out_col + j] = hj;                     \
    (VIN) = nI;                                                         \
} while (0)

extern "C" __global__ void __launch_bounds__(256, 2) k23_sgpr(
    const float* __restrict__ Wih, const float* __restrict__ Whh,
    const float* __restrict__ bih, const float* __restrict__ bhh,
    float* __restrict__ out, int in_col, int out_col)
{
    const int tid = threadIdx.x;
    const int w = tid >> 6, l = tid & 63, j = l & 31;
    const bool hi = l >= 32;

    float wI[32], wH[32], wNI[32], wNH[32];
    const int rA = (hi ? 32 : 0) + j;
    #pragma unroll
    for (int k = 0; k < 32; ++k) {
        wI[k]  = Wih[rA * 32 + k];                        // Wir / Wiz
        wH[k]  = Whh[rA * 32 + k];                        // Whr / Whz
        wNI[k] = hi ? 0.f : Wih[(64 + j) * 32 + k];       // Win (lo)
        wNH[k] = hi ? Whh[(64 + j) * 32 + k] : 0.f;       // Whn (hi)
    }
    #pragma unroll
    for (int k = 0; k < 32; ++k) {
        KEEPV(wI[k]); KEEPV(wH[k]); KEEPV(wNI[k]); KEEPV(wNH[k]);
    }
    const float bA = bih[rA] + bhh[rA];
    const float bN = hi ? bhh[64 + j] : bih[64 + j];

    const size_t b = (size_t)blockIdx.x * 4 + w;
    float* orow = out + b * (size_t)(TT * VV);
    const float* irow = orow + in_col;

    float vh = 0.f, hj = 0.f;
    float I0 = irow[0 * VV + j], I1 = irow[1 * VV + j];
    float I2 = irow[2 * VV + j], I3 = irow[3 * VV + j];

    for (int t = 0; t < TT; t += 4) {
        K23S(t + 0, I0);
        K23S(t + 1, I1);
        K23S(t + 2, I2);
        K23S(t + 3, I3);
    }
}

// ================= K4: FC GEMM. reads h3 from cols 0:32, writes all 95 cols in-place
__global__ void __launch_bounds__(256) k4_fc(
    const float* __restrict__ Wfc, const float* __restrict__ bfc,
    float* __restrict__ out)
{
    __shared__ float hs[64 * 36];
    __shared__ float ws[96 * 36];
    const int tid = threadIdx.x;
    const size_t row0 = (size_t)blockIdx.x * 64;

    for (int i = tid; i < 64 * 32; i += 256) {
        const int r = i >> 5, k = i & 31;
        hs[r * 36 + k] = out[(row0 + r) * VV + k];
    }
    for (int i = tid; i < 95 * 32; i += 256) {
        const int g = i >> 5, k = i & 31;
        ws[g * 36 + k] = Wfc[i];
    }
    for (int i = tid; i < 32; i += 256) ws[95 * 36 + i] = 0.f;
    const int cq = tid & 15, rq = tid >> 4;
    float acc[4][6];
    #pragma unroll
    for (int c = 0; c < 6; ++c) {
        const int g = cq + 16 * c;
        const float bv = (g < VV) ? bfc[g] : 0.f;
        acc[0][c] = bv; acc[1][c] = bv; acc[2][c] = bv; acc[3][c] = bv;
    }
    __syncthreads();

    #pragma unroll
    for (int k4 = 0; k4 < 8; ++k4) {
        const int k = k4 * 4;
        const float4 h0 = *(const float4*)(hs + (rq     ) * 36 + k);
        const float4 h1 = *(const float4*)(hs + (rq + 16) * 36 + k);
        const float4 h2 = *(const float4*)(hs + (rq + 32) * 36 + k);
        const float4 h3 = *(const float4*)(hs + (rq + 48) * 36 + k);
        #pragma unroll
        for (int c = 0; c < 6; ++c) {
            const float4 wv = *(const float4*)(ws + (cq + 16 * c) * 36 + k);
            acc[0][c] = fmaf(h0.x, wv.x, acc[0][c]); acc[0][c] = fmaf(h0.y, wv.y, acc[0][c]);
            acc[0][c] = fmaf(h0.z, wv.z, acc[0][c]); acc[0][c] = fmaf(h0.w, wv.w, acc[0][c]);
            acc[1][c] = fmaf(h1.x, wv.x, acc[1][c]); acc[1][c] = fmaf(h1.y, wv.y, acc[1][c]);
            acc[1][c] = fmaf(h1.z, wv.z, acc[1][c]); acc[1][c] = fmaf(h1.w, wv.w, acc[1][c]);
            acc[2][c] = fmaf(h2.x, wv.x, acc[2][c]); acc[2][c] = fmaf(h2.y, wv.y, acc[2][c]);
            acc[2][c] = fmaf(h2.z, wv.z, acc[2][c]); acc[2][c] = fmaf(h2.w, wv.w, acc[2][c]);
            acc[3][c] = fmaf(h3.x, wv.x, acc[3][c]); acc[3][c] = fmaf(h3.y, wv.y, acc[3][c]);
            acc[3][c] = fmaf(h3.z, wv.z, acc[3][c]); acc[3][c] = fmaf(h3.w, wv.w, acc[3][c]);
        }
    }
    #pragma unroll
    for (int r = 0; r < 4; ++r) {
        float* orow = out + (row0 + rq + 16 * r) * VV;
        #pragma unroll
        for (int c = 0; c < 6; ++c) {
            const int g = cq + 16 * c;
            if (g < VV) orow[g] = acc[r][c];
        }
    }
}

extern "C" void kernel_launch(void* const* d_in, const int* in_sizes, int n_in,
                              void* d_out, int out_size, void* d_ws, size_t ws_size,
                              hipStream_t stream) {
    const float* x    = (const float*)d_in[0];
    const float* Wih1 = (const float*)d_in[1];
    const float* Whh1 = (const float*)d_in[2];
    const float* bih1 = (const float*)d_in[3];
    const float* bhh1 = (const float*)d_in[4];
    const float* Wih2 = (const float*)d_in[5];
    const float* Whh2 = (const float*)d_in[6];
    const float* bih2 = (const float*)d_in[7];
    const float* bhh2 = (const float*)d_in[8];
    const float* Wih3 = (const float*)d_in[9];
    const float* Whh3 = (const float*)d_in[10];
    const float* bih3 = (const float*)d_in[11];
    const float* bhh3 = (const float*)d_in[12];
    const float* Wfc  = (const float*)d_in[13];
    const float* bfc  = (const float*)d_in[14];
    float* out = (float*)d_out;
    float* ws95 = (float*)d_ws;

    const int use_ws = (ws_size >= (size_t)2048 * 256 * 4) ? 1 : 0;

    hipLaunchKernelGGL(k0_xproj, dim3(8192), dim3(256), 0, stream,
                       x, Wih1, bih1, out, ws95, use_ws);
    if (use_ws)
        hipLaunchKernelGGL(k1_sgpr, dim3(512), dim3(256), 0, stream, Whh1, bhh1, ws95, out);
    else
        hipLaunchKernelGGL(k1_l1_fb, dim3(512), dim3(256), 0, stream,
                           x, Wih1, Whh1, bih1, bhh1, out);
    hipLaunchKernelGGL(k23_sgpr, dim3(512), dim3(256), 0, stream,
                       Wih2, Whh2, bih2, bhh2, out, 0, 32);
    hipLaunchKernelGGL(k23_sgpr, dim3(512), dim3(256), 0, stream,
                       Wih3, Whh3, bih3, bhh3, out, 32, 0);
    hipLaunchKernelGGL(k4_fc, dim3(8192), dim3(256), 0, stream, Wfc, bfc, out);
}